// Round 1
// baseline (223.562 us; speedup 1.0000x reference)
//
#include <hip/hip_runtime.h>

// ---------------------------------------------------------------------------
// CapsNet dynamic routing, fully fused, fp32.
//   x: [B=64, I=8192, N=8]   W: [I=8192, J=8, N=8, M=16]   out: [B, J=8, M=16]
//
// Algebra: b_logits after t iters = dot(sum_{t' <= t} v_{t'}, u_hat), so we
// only carry vsum[B,J,M] (32 KB) between passes and recompute u_hat per pass
// from x,W (both L3-resident). u_hat (268 MB) is NEVER materialized.
//
// Pass kernel: 256 blocks x 512 threads. Block = all 64 b  x  32-i chunk.
//   thread = (b, g) with g = jh*4+mq: covers j in [jh*4, jh*4+4), m in [mq*4, mq*4+4)
//   W[i] staged in LDS (8 i's per stage, padded j-stride to spread banks),
//   broadcast-read across the 64 b's. Partial s stored per block (no atomics).
// Reduce kernel: sums 256 partials, squash, updates vsum (or writes d_out).
// ---------------------------------------------------------------------------

#define BB      64
#define ICAPS   8192
#define NDIM    8
#define JCAPS   8
#define MDIM    16
#define NBLK    256
#define ICHUNK  (ICAPS / NBLK)        // 32
#define IG      8                     // i's staged per barrier
#define NSTAGE  (ICHUNK / IG)         // 4
#define JW      4                     // j per thread
#define MW      4                     // m per thread
#define WJ_STRIDE (NDIM * MDIM + 4)   // 132 floats: pad to spread LDS banks
#define WI_STRIDE (JCAPS * WJ_STRIDE) // 1056 floats per i
#define S_ELEMS  (BB * JCAPS * MDIM)  // 8192 floats per s / vsum / out

// MODE 0: uniform c = 1/8 (first routing iteration; softmax of zeros)
// MODE 1: c = softmax_j( dot(vsum[b,j,:], u_hat[b,i,j,:]) )
template <int MODE>
__global__ __launch_bounds__(512, 1) void caps_pass_kernel(
    const float* __restrict__ x, const float* __restrict__ W,
    const float* __restrict__ vsum, float* __restrict__ partial)
{
    __shared__ float Wlds[IG * WI_STRIDE];   // 33,792 B

    const int tid = threadIdx.x;             // 0..511
    const int b   = tid >> 3;                // 0..63
    const int g   = tid & 7;
    const int jh  = g >> 2;                  // 0..1   (j half)
    const int mq  = g & 3;                   // 0..3   (m quad)
    const int blk = blockIdx.x;
    const int i0  = blk * ICHUNK;

    float s_acc[JW][MW];
    #pragma unroll
    for (int a = 0; a < JW; ++a)
        #pragma unroll
        for (int c = 0; c < MW; ++c) s_acc[a][c] = 0.f;

    float vreg[JW][MW];
    if (MODE == 1) {
        #pragma unroll
        for (int jj = 0; jj < JW; ++jj) {
            const float4 vv = *(const float4*)&vsum[(b * JCAPS + jh * JW + jj) * MDIM + mq * 4];
            vreg[jj][0] = vv.x; vreg[jj][1] = vv.y; vreg[jj][2] = vv.z; vreg[jj][3] = vv.w;
        }
    }

    for (int st = 0; st < NSTAGE; ++st) {
        // ---- stage W for IG i's into LDS (each thread: one 16-float m-row) ----
        {
            const int iL  = tid >> 6;        // 0..7
            const int rem = tid & 63;
            const int j   = rem >> 3;        // 0..7
            const int n   = rem & 7;         // 0..7
            const float4* src = (const float4*)(W + (size_t)(i0 + st * IG + iL) * 1024
                                                  + j * 128 + n * 16);
            float4* dst = (float4*)&Wlds[iL * WI_STRIDE + j * WJ_STRIDE + n * 16];
            dst[0] = src[0]; dst[1] = src[1]; dst[2] = src[2]; dst[3] = src[3];
        }
        __syncthreads();

        #pragma unroll
        for (int ii = 0; ii < IG; ++ii) {
            const int i = i0 + st * IG + ii;
            const float4 xa = *(const float4*)&x[((size_t)b * ICAPS + i) * NDIM];
            const float4 xb = *(const float4*)&x[((size_t)b * ICAPS + i) * NDIM + 4];
            const float xs[8] = {xa.x, xa.y, xa.z, xa.w, xb.x, xb.y, xb.z, xb.w};

            // u_hat fragment: j in [jh*4, jh*4+4), m in [mq*4, mq*4+4)
            float u[JW][MW] = {};
            const float* wbase = &Wlds[ii * WI_STRIDE + (jh * JW) * WJ_STRIDE + mq * 4];
            #pragma unroll
            for (int jj = 0; jj < JW; ++jj) {
                #pragma unroll
                for (int n = 0; n < NDIM; ++n) {
                    const float4 wq = *(const float4*)&wbase[jj * WJ_STRIDE + n * MDIM];
                    u[jj][0] += xs[n] * wq.x;
                    u[jj][1] += xs[n] * wq.y;
                    u[jj][2] += xs[n] * wq.z;
                    u[jj][3] += xs[n] * wq.w;
                }
            }

            if (MODE == 0) {
                #pragma unroll
                for (int jj = 0; jj < JW; ++jj)
                    #pragma unroll
                    for (int mm = 0; mm < MW; ++mm) s_acc[jj][mm] += u[jj][mm];
            } else {
                // logits: lp[jj] = dot_m(v[b,j,:], u[b,i,j,:]) — partial over m-quad
                float lp[JW];
                #pragma unroll
                for (int jj = 0; jj < JW; ++jj)
                    lp[jj] = u[jj][0] * vreg[jj][0] + u[jj][1] * vreg[jj][1]
                           + u[jj][2] * vreg[jj][2] + u[jj][3] * vreg[jj][3];
                // reduce over the 4 mq lanes (lanes differ in bits 0,1 of g)
                #pragma unroll
                for (int jj = 0; jj < JW; ++jj) {
                    lp[jj] += __shfl_xor(lp[jj], 1);
                    lp[jj] += __shfl_xor(lp[jj], 2);
                }
                // exchange with the other j-half (bit 2 of g)
                float lo[JW];
                #pragma unroll
                for (int jj = 0; jj < JW; ++jj) lo[jj] = __shfl_xor(lp[jj], 4);
                // softmax over all 8 j (each thread has all 8 logits)
                float mx = lp[0];
                #pragma unroll
                for (int jj = 1; jj < JW; ++jj) mx = fmaxf(mx, lp[jj]);
                #pragma unroll
                for (int jj = 0; jj < JW; ++jj) mx = fmaxf(mx, lo[jj]);
                float e[JW];
                float den = 0.f;
                #pragma unroll
                for (int jj = 0; jj < JW; ++jj) {
                    e[jj] = __expf(lp[jj] - mx);
                    den += e[jj];
                    den += __expf(lo[jj] - mx);
                }
                const float inv = 1.0f / den;
                #pragma unroll
                for (int jj = 0; jj < JW; ++jj) {
                    const float c = e[jj] * inv;
                    #pragma unroll
                    for (int mm = 0; mm < MW; ++mm) s_acc[jj][mm] += c * u[jj][mm];
                }
            }
        }
        __syncthreads();
    }

    // ---- store block-partial s: partial[blk][b][j][m] ----
    const float sc = (MODE == 0) ? 0.125f : 1.0f;
    float* pp = partial + (size_t)blk * S_ELEMS + b * (JCAPS * MDIM);
    #pragma unroll
    for (int jj = 0; jj < JW; ++jj) {
        float4 o;
        o.x = s_acc[jj][0] * sc; o.y = s_acc[jj][1] * sc;
        o.z = s_acc[jj][2] * sc; o.w = s_acc[jj][3] * sc;
        *(float4*)&pp[(jh * JW + jj) * MDIM + mq * 4] = o;
    }
}

// Sum 256 partials -> s[b,j,m]; v = squash(s); FINAL: write d_out, else vsum += v.
template <int FINAL>
__global__ __launch_bounds__(256) void caps_reduce_kernel(
    const float* __restrict__ partial, float* __restrict__ vsum, float* __restrict__ out)
{
    __shared__ float sd[256];
    const int bo  = blockIdx.x;     // 0..255, each block covers 32 outputs
    const int tid = threadIdx.x;
    const int tl  = tid >> 3;       // 0..31 output-within-block
    const int kg  = tid & 7;        // 0..7  slot-group
    const int t   = bo * 32 + tl;   // global output index (= b*128 + j*16 + m)

    float ssum = 0.f;
    const float* p = partial + (size_t)kg * 32 * S_ELEMS + t;
    #pragma unroll
    for (int k = 0; k < 32; ++k) ssum += p[(size_t)k * S_ELEMS];
    sd[tid] = ssum;
    __syncthreads();

    if (tid < 32) {
        const int tt = bo * 32 + tid;
        float s = 0.f;
        #pragma unroll
        for (int q = 0; q < 8; ++q) s += sd[tid * 8 + q];
        // squash: sn over the 16 m's of this (b,j) — lanes tid grouped by 16
        float sn = s * s;
        sn += __shfl_xor(sn, 1);
        sn += __shfl_xor(sn, 2);
        sn += __shfl_xor(sn, 4);
        sn += __shfl_xor(sn, 8);
        const float v = s * sqrtf(sn) / (1.f + sn);
        if (FINAL) out[tt] = v;
        else       vsum[tt] += v;
    }
}

extern "C" void kernel_launch(void* const* d_in, const int* in_sizes, int n_in,
                              void* d_out, int out_size, void* d_ws, size_t ws_size,
                              hipStream_t stream)
{
    const float* x = (const float*)d_in[0];   // [64, 8192, 8]
    const float* W = (const float*)d_in[1];   // [8192, 8, 8, 16]
    float* out = (float*)d_out;               // [64, 8, 16]

    float* partial = (float*)d_ws;                              // 256 * 8192 floats = 8 MB
    float* vsum    = partial + (size_t)NBLK * S_ELEMS;          // 8192 floats

    // vsum accumulates v_1 + v_2 (ws is poisoned each call -> zero it)
    hipMemsetAsync(vsum, 0, S_ELEMS * sizeof(float), stream);

    // pass 1: c uniform
    caps_pass_kernel<0><<<NBLK, 512, 0, stream>>>(x, W, vsum, partial);
    caps_reduce_kernel<0><<<256, 256, 0, stream>>>(partial, vsum, nullptr);  // vsum = v1
    // pass 2: logits = dot(v1, u_hat)
    caps_pass_kernel<1><<<NBLK, 512, 0, stream>>>(x, W, vsum, partial);
    caps_reduce_kernel<0><<<256, 256, 0, stream>>>(partial, vsum, nullptr);  // vsum = v1+v2
    // pass 3 (final): logits = dot(v1+v2, u_hat), output squash
    caps_pass_kernel<1><<<NBLK, 512, 0, stream>>>(x, W, vsum, partial);
    caps_reduce_kernel<1><<<256, 256, 0, stream>>>(partial, vsum, out);
}